// Round 4
// baseline (138.996 us; speedup 1.0000x reference)
//
#include <hip/hip_runtime.h>
#include <math.h>

#ifndef M_PI
#define M_PI 3.14159265358979323846
#endif

#define DMODEL 256
#define NSTATE 64
#define LSEQ   8192
#define INVL   (1.0f/8192.0f)

// Workspace layout (bytes). Total ~17.6 MB.
#define OFF_TW  0                                  // float2[6144]: e^{+2pi i j/L}
#define OFF_DN  (6144*8)                           // float4[3*DMODEL*NSTATE]
#define OFF_CDT (OFF_DN + DMODEL*NSTATE*48)        // float[DMODEL]: 2/dt
#define OFF_KT  (OFF_CDT + 1024)                   // float4[DMODEL*4096]: radix-2'd, digit-reversed K_hat/L

__device__ __forceinline__ float sin_rev(float r) {
#if __has_builtin(__builtin_amdgcn_sinf)
  return __builtin_amdgcn_sinf(r);        // sin(S0 * 2pi)
#else
  return __sinf(r * 6.283185307179586f);
#endif
}
__device__ __forceinline__ float cos_rev(float r) {
#if __has_builtin(__builtin_amdgcn_cosf)
  return __builtin_amdgcn_cosf(r);
#else
  return __cosf(r * 6.283185307179586f);
#endif
}

__device__ __forceinline__ float2 cmul(float2 a, float2 b) {
  return make_float2(a.x*b.x - a.y*b.y, a.x*b.y + a.y*b.x);
}

// LDS anti-conflict swizzle: bijective on [0,8192), keeps (2i,2i+1) adjacent
// and float4 alignment (bit0 untouched). Spreads s&15 so every stage of the
// radix-4 FFT sits at the 8B-access bank floor instead of 8/16-way.
__device__ __forceinline__ int swz(int i) { return i ^ ((i >> 3) & 0xE); }

// K_hat/L from the 4 complex sums. PRB*BRP = S1^2 + S2^2 (complex squares).
// Prefactor 2/(1+z) = 1 + i*T; fold 1/L here.
__device__ __forceinline__ float2 woodbury(float2 S1, float2 S2, float2 S3,
                                           float2 S4, float T) {
  float nr = (S1.x*S1.x - S1.y*S1.y) + (S2.x*S2.x - S2.y*S2.y);
  float ni = 2.0f*(S1.x*S1.y + S2.x*S2.y);
  float dr = 1.0f + S3.x, di = S3.y;
  float inv = __builtin_amdgcn_rcpf(fmaf(dr, dr, di*di));
  float qr = (nr*dr + ni*di) * inv;
  float qi = (ni*dr - nr*di) * inv;
  float vr = S4.x - qr, vi = S4.y - qi;
  return make_float2((vr - T*vi)*INVL, (vi + T*vr)*INVL);
}

// ---------------------------------------------------------------- precompute
__global__ __launch_bounds__(256) void precompute_kernel(
    const float* __restrict__ Lre, const float* __restrict__ Lim,
    const float* __restrict__ Pre, const float* __restrict__ Pim,
    const float* __restrict__ Bre, const float* __restrict__ Bim,
    const float* __restrict__ log_dt, char* __restrict__ ws)
{
  const int t = blockIdx.x * blockDim.x + threadIdx.x;  // 0..16383
  float2* tw  = (float2*)(ws + OFF_TW);
  float4* dn  = (float4*)(ws + OFF_DN);
  float*  cdt = (float*)(ws + OFF_CDT);

  if (t < 6144) {
    double th = (2.0 * M_PI / (double)LSEQ) * (double)t;
    double s, c; sincos(th, &s, &c);
    tw[t] = make_float2((float)c, (float)s);
  }
  {
    float lre = Lre[t], lim = Lim[t];
    float pre = Pre[t], pim = Pim[t];
    float bre = Bre[t], bim = Bim[t];
    float sp = fmaxf(lre, 0.0f) + log1pf(expf(-fabsf(lre)));  // softplus
    float w1r = pre*bre + pim*bim;   // Re conj(P)*B
    float w1i = pre*bim - pim*bre;   // Im conj(P)*B
    float w2  = pre*pre + pim*pim;   // |P|^2
    float w3  = bre*bre + bim*bim;   // |B|^2
    dn[3*t]   = make_float4(lim, sp*sp, w1r*sp, w1i*sp);
    dn[3*t+1] = make_float4(w2*sp, w3*sp, w1r, w1i);
    dn[3*t+2] = make_float4(w2, w3, 0.0f, 0.0f);
  }
  if (t < DMODEL) cdt[t] = 2.0f * expf(-log_dt[t]);
}

// ---------------------------------------------------------------- cauchy
// No LDS. Each thread evaluates FOUR k-points: pairs p=b and p=b+2048
// (kA' = kA + 2 under the digit-reversal), amortizing the per-n table loads
// and loop overhead over 4x the FMA work. Writes post-radix-2 {sum, diff}
// linearly (the FFT's natural input). Grid = exactly one wave-round.
__global__ __launch_bounds__(256, 4) void cauchy_kernel(
    const float4* __restrict__ dn_all, const float* __restrict__ cdt,
    float4* __restrict__ kt)
{
  const int d = blockIdx.y;
  const int b = blockIdx.x * 256 + threadIdx.x;   // 0..2047 (pair ids b, b+2048)
  const float4* dn = dn_all + (size_t)d * (3*NSTATE);
  const float c = cdt[d];                         // 2/dt, wave-uniform

  const unsigned r = __brev((unsigned)(2*b)) >> 19;               // 13-bit rev
  const int kA0 = (int)(((r & 0x0555u) << 1) | ((r & 0x0AAAu) >> 1));
  const int kA1 = kA0 + 2;                        // pair b+2048 maps to kA+2
  // T = tan(pi k/L); (1-z)/(1+z) = i*T, 2/(1+z) = 1 + i*T (exact identities)
  const float rev0 = (float)kA0 * (1.0f/16384.0f);
  const float rev1 = (float)kA1 * (1.0f/16384.0f);
  const float s0 = sin_rev(rev0), c0 = cos_rev(rev0);
  const float s1 = sin_rev(rev1), c1 = cos_rev(rev1);
  float TA0 =  s0 * __builtin_amdgcn_rcpf(c0);
  float TB0 = -c0 * __builtin_amdgcn_rcpf(s0);    // tan(x+pi/2) = -cot(x)
  float TA1 =  s1 * __builtin_amdgcn_rcpf(c1);
  float TB1 = -c1 * __builtin_amdgcn_rcpf(s1);
  TA0 = fminf(fmaxf(TA0, -1e7f), 1e7f);
  TB0 = fminf(fmaxf(TB0, -1e7f), 1e7f);
  TA1 = fminf(fmaxf(TA1, -1e7f), 1e7f);
  TB1 = fminf(fmaxf(TB1, -1e7f), 1e7f);
  const float gA0 = c*TA0, gB0 = c*TB0, gA1 = c*TA1, gB1 = c*TB1;

  float2 S1a0={0,0}, S2a0={0,0}, S3a0={0,0}, S4a0={0,0};
  float2 S1b0={0,0}, S2b0={0,0}, S3b0={0,0}, S4b0={0,0};
  float2 S1a1={0,0}, S2a1={0,0}, S3a1={0,0}, S4a1={0,0};
  float2 S1b1={0,0}, S2b1={0,0}, S3b1={0,0}, S4b1={0,0};

#pragma unroll 2
  for (int n = 0; n < NSTATE; ++n) {
    const float4 q0 = dn[3*n];      // lam_im, sp^2, w1r*sp, w1i*sp  (s_load)
    const float4 q1 = dn[3*n+1];    // w2*sp, w3*sp, w1r, w1i
    const float4 q2 = dn[3*n+2];    // w2, w3, -, -
#define CPOINT(G, S1, S2, S3, S4)                                          \
    {                                                                      \
      const float dim = (G) - q0.x;                                        \
      const float inv = __builtin_amdgcn_rcpf(fmaf(dim, dim, q0.y));       \
      const float dI  = dim * inv;                                         \
      S1.x = fmaf(q0.z, inv, S1.x);  S1.y = fmaf(q1.z, -dI, S1.y);         \
      S2.x = fmaf(q0.w, inv, S2.x);  S2.y = fmaf(q1.w, -dI, S2.y);         \
      S3.x = fmaf(q1.x, inv, S3.x);  S3.y = fmaf(q2.x, -dI, S3.y);         \
      S4.x = fmaf(q1.y, inv, S4.x);  S4.y = fmaf(q2.y, -dI, S4.y);         \
    }
    CPOINT(gA0, S1a0, S2a0, S3a0, S4a0)
    CPOINT(gB0, S1b0, S2b0, S3b0, S4b0)
    CPOINT(gA1, S1a1, S2a1, S3a1, S4a1)
    CPOINT(gB1, S1b1, S2b1, S3b1, S4b1)
#undef CPOINT
  }
  const float2 KA0 = woodbury(S1a0, S2a0, S3a0, S4a0, TA0);
  const float2 KB0 = woodbury(S1b0, S2b0, S3b0, S4b0, TB0);
  const float2 KA1 = woodbury(S1a1, S2a1, S3a1, S4a1, TA1);
  const float2 KB1 = woodbury(S1b1, S2b1, S3b1, S4b1, TB1);
  float4* orow = kt + (size_t)d * 4096;
  orow[b]        = make_float4(KA0.x + KB0.x, KA0.y + KB0.y,
                               KA0.x - KB0.x, KA0.y - KB0.y);
  orow[b + 2048] = make_float4(KA1.x + KB1.x, KA1.y + KB1.y,
                               KA1.x - KB1.x, KA1.y - KB1.y);
}

// ---------------------------------------------------------------- ifft
// Input already radix-2'd and digit-reversed -> linear float4 load into
// swizzled LDS, 6 radix-4 DIT stages, natural-order real output.
__global__ __launch_bounds__(1024) void ifft_kernel(
    const float4* __restrict__ kt, const float2* __restrict__ tw,
    const float* __restrict__ Din, float* __restrict__ out)
{
  __shared__ __align__(16) float2 xy[LSEQ];   // 64 KB
  const int d = blockIdx.x;
  const int t = threadIdx.x;                  // 0..1023
  const float4* row = kt + (size_t)d * 4096;

  for (int i = t; i < 4096; i += 1024) {
    const float4 v = row[i];
    *(float4*)&xy[swz(2*i)] = v;              // swz keeps the pair adjacent+aligned
  }
  __syncthreads();

#pragma unroll
  for (int s = 0; s < 6; ++s) {
    const int h = 2 << (2*s);
    const int twsh = 10 - 2*s;                // tw stride = L/(4h)
#pragma unroll
    for (int j = 0; j < 2; ++j) {
      const int bb = t + (j << 10);           // butterfly id 0..2047
      const int pos = bb & (h - 1);
      const int i0 = ((bb >> (1 + 2*s)) << (3 + 2*s)) + pos;
      const int a0 = swz(i0);
      const int a1 = swz(i0 + h);
      const int a2 = swz(i0 + 2*h);
      const int a3 = swz(i0 + 3*h);
      const int ti = pos << twsh;
      const float2 w1 = tw[ti];
      const float2 w2 = tw[2*ti];
      const float2 w3 = tw[3*ti];
      const float2 x0 = xy[a0];
      const float2 x1 = xy[a1];
      const float2 x2 = xy[a2];
      const float2 x3 = xy[a3];
      const float2 t1 = cmul(w1, x1);
      const float2 t2 = cmul(w2, x2);
      const float2 t3 = cmul(w3, x3);
      const float2 u0 = make_float2(x0.x + t2.x, x0.y + t2.y);
      const float2 u1 = make_float2(x0.x - t2.x, x0.y - t2.y);
      const float2 u2 = make_float2(t1.x + t3.x, t1.y + t3.y);
      const float2 vv = make_float2(t1.x - t3.x, t1.y - t3.y);
      xy[a0] = make_float2(u0.x + u2.x, u0.y + u2.y);   // Y0
      xy[a1] = make_float2(u1.x - vv.y, u1.y + vv.x);   // Y1 = u1 + i*vv
      xy[a2] = make_float2(u0.x - u2.x, u0.y - u2.y);   // Y2
      xy[a3] = make_float2(u1.x + vv.y, u1.y - vv.x);   // Y3 = u1 - i*vv
    }
    __syncthreads();
  }

  float* orow = out + (size_t)d * LSEQ;
  for (int i = t; i < LSEQ; i += 1024) orow[i] = xy[swz(i)].x;

  // second tuple output: D passthrough (zeros buffer)
  if (d == 0 && t < DMODEL) out[(size_t)DMODEL * LSEQ + t] = Din[t];
}

// ---------------------------------------------------------------- launch
extern "C" void kernel_launch(void* const* d_in, const int* in_sizes, int n_in,
                              void* d_out, int out_size, void* d_ws, size_t ws_size,
                              hipStream_t stream)
{
  const float* Lre    = (const float*)d_in[0];
  const float* Lim    = (const float*)d_in[1];
  const float* Pre    = (const float*)d_in[2];
  const float* Pim    = (const float*)d_in[3];
  const float* Bre    = (const float*)d_in[4];
  const float* Bim    = (const float*)d_in[5];
  const float* log_dt = (const float*)d_in[6];
  const float* Din    = (const float*)d_in[7];
  float* out = (float*)d_out;
  char* ws = (char*)d_ws;

  hipLaunchKernelGGL(precompute_kernel, dim3(64), dim3(256), 0, stream,
                     Lre, Lim, Pre, Pim, Bre, Bim, log_dt, ws);
  hipLaunchKernelGGL(cauchy_kernel, dim3(8, DMODEL), dim3(256), 0, stream,
                     (const float4*)(ws + OFF_DN), (const float*)(ws + OFF_CDT),
                     (float4*)(ws + OFF_KT));
  hipLaunchKernelGGL(ifft_kernel, dim3(DMODEL), dim3(1024), 0, stream,
                     (const float4*)(ws + OFF_KT), (const float2*)(ws + OFF_TW),
                     Din, out);
}

// Round 6
// 126.092 us; speedup vs baseline: 1.1023x; 1.1023x over previous
//
#include <hip/hip_runtime.h>
#include <math.h>

#ifndef M_PI
#define M_PI 3.14159265358979323846
#endif

#define DMODEL 256
#define NSTATE 64
#define LSEQ   8192
#define INVL   (1.0f/8192.0f)

typedef float v2f __attribute__((ext_vector_type(2)));

// Workspace layout (bytes). Total ~17.6 MB.
#define OFF_TW  0                                  // float2[6144]: e^{+2pi i j/L}
#define OFF_DN  (6144*8)                           // float4[3*DMODEL*NSTATE]
#define OFF_CDT (OFF_DN + DMODEL*NSTATE*48)        // float[DMODEL]: 2/dt
#define OFF_KT  (OFF_CDT + 1024)                   // float4[DMODEL*4096]: radix-2'd, digit-reversed K_hat/L

__device__ __forceinline__ float sin_rev(float r) {
#if __has_builtin(__builtin_amdgcn_sinf)
  return __builtin_amdgcn_sinf(r);        // sin(S0 * 2pi)
#else
  return __sinf(r * 6.283185307179586f);
#endif
}
__device__ __forceinline__ float cos_rev(float r) {
#if __has_builtin(__builtin_amdgcn_cosf)
  return __builtin_amdgcn_cosf(r);
#else
  return __cosf(r * 6.283185307179586f);
#endif
}

__device__ __forceinline__ float2 cmul(float2 a, float2 b) {
  return make_float2(a.x*b.x - a.y*b.y, a.x*b.y + a.y*b.x);
}

// K_hat/L from the 4 complex sums. PRB*BRP = S1^2 + S2^2 (complex squares).
// Prefactor 2/(1+z) = 1 + i*T; fold 1/L here.
__device__ __forceinline__ float2 woodbury(float2 S1, float2 S2, float2 S3,
                                           float2 S4, float T) {
  float nr = (S1.x*S1.x - S1.y*S1.y) + (S2.x*S2.x - S2.y*S2.y);
  float ni = 2.0f*(S1.x*S1.y + S2.x*S2.y);
  float dr = 1.0f + S3.x, di = S3.y;
  float inv = __builtin_amdgcn_rcpf(fmaf(dr, dr, di*di));
  float qr = (nr*dr + ni*di) * inv;
  float qi = (ni*dr - nr*di) * inv;
  float vr = S4.x - qr, vi = S4.y - qi;
  return make_float2((vr - T*vi)*INVL, (vi + T*vr)*INVL);
}

// ---------------------------------------------------------------- precompute
__global__ __launch_bounds__(256) void precompute_kernel(
    const float* __restrict__ Lre, const float* __restrict__ Lim,
    const float* __restrict__ Pre, const float* __restrict__ Pim,
    const float* __restrict__ Bre, const float* __restrict__ Bim,
    const float* __restrict__ log_dt, char* __restrict__ ws)
{
  const int t = blockIdx.x * blockDim.x + threadIdx.x;  // 0..16383
  float2* tw  = (float2*)(ws + OFF_TW);
  float4* dn  = (float4*)(ws + OFF_DN);
  float*  cdt = (float*)(ws + OFF_CDT);

  if (t < 6144) {
    double th = (2.0 * M_PI / (double)LSEQ) * (double)t;
    double s, c; sincos(th, &s, &c);
    tw[t] = make_float2((float)c, (float)s);
  }
  {
    float lre = Lre[t], lim = Lim[t];
    float pre = Pre[t], pim = Pim[t];
    float bre = Bre[t], bim = Bim[t];
    float sp = fmaxf(lre, 0.0f) + log1pf(expf(-fabsf(lre)));  // softplus
    float w1r = pre*bre + pim*bim;   // Re conj(P)*B
    float w1i = pre*bim - pim*bre;   // Im conj(P)*B
    float w2  = pre*pre + pim*pim;   // |P|^2
    float w3  = bre*bre + bim*bim;   // |B|^2
    dn[3*t]   = make_float4(lim, sp*sp, w1r*sp, w1i*sp);
    dn[3*t+1] = make_float4(w2*sp, w3*sp, w1r, w1i);
    dn[3*t+2] = make_float4(w2, w3, 0.0f, 0.0f);
  }
  if (t < DMODEL) cdt[t] = 2.0f * expf(-log_dt[t]);
}

// ---------------------------------------------------------------- cauchy
// No LDS -> 8 waves/SIMD. Thread = pair (kA, kA+4096), kA digit-reversed.
// A/B points packed lane-wise into v2f -> v_pk_fma_f32 (2x FP32 rate) with
// SGPR broadcasts as multiplicands; ONE v_rcp per pair via rcp(magA*magB)
// (safe: tan*cot = -1 keeps the product far from fp32 overflow).
// Writes post-radix-2 {sum, diff} linearly (the FFT's natural input).
__global__ __launch_bounds__(256, 8) void cauchy_kernel(
    const float4* __restrict__ dn_all, const float* __restrict__ cdt,
    float4* __restrict__ kt)
{
  const int d = blockIdx.y;
  const int b = blockIdx.x * 256 + threadIdx.x;   // 0..4095 pair id
  const float4* dn = dn_all + (size_t)d * (3*NSTATE);
  const float c = cdt[d];                         // 2/dt, wave-uniform

  const unsigned r = __brev((unsigned)(2*b)) >> 19;             // 13-bit rev
  const int kA = (int)(((r & 0x0555u) << 1) | ((r & 0x0AAAu) >> 1));  // pair-swap
  // T = tan(pi k/L); (1-z)/(1+z) = i*T, 2/(1+z) = 1 + i*T (exact identities)
  const float rev = (float)kA * (1.0f/16384.0f);  // < 0.25 revolutions
  const float sA = sin_rev(rev), cA = cos_rev(rev);
  float TA =  sA * __builtin_amdgcn_rcpf(cA);
  float TB = -cA * __builtin_amdgcn_rcpf(sA);     // tan(x + pi/2) = -cot(x)
  TA = fminf(fmaxf(TA, -1e7f), 1e7f);
  TB = fminf(fmaxf(TB, -1e7f), 1e7f);
  const v2f g2 = {c * TA, c * TB};                // g purely imaginary, A|B packed

  v2f S1x = {0,0}, S1y = {0,0}, S2x = {0,0}, S2y = {0,0};
  v2f S3x = {0,0}, S3y = {0,0}, S4x = {0,0}, S4y = {0,0};

#pragma unroll 4
  for (int n = 0; n < NSTATE; ++n) {
    const float4 q0 = dn[3*n];      // lam_im, sp^2, w1r*sp, w1i*sp  (s_load)
    const float4 q1 = dn[3*n+1];    // w2*sp, w3*sp, w1r, w1i
    const float4 q2 = dn[3*n+2];    // w2, w3, -, -
    const v2f dim = g2 - q0.x;                                    // pk_add
    const v2f mag = __builtin_elementwise_fma(dim, dim, (v2f)(q0.y)); // pk_fma
    const float p = mag.x * mag.y;
    const float rp = __builtin_amdgcn_rcpf(p);
    const v2f inv = rp * (v2f){mag.y, mag.x};                     // pk_mul (op_sel swap)
    const v2f dI  = dim * inv;                                    // pk_mul
    S1x = __builtin_elementwise_fma((v2f)(q0.z), inv, S1x);
    S1y = __builtin_elementwise_fma((v2f)(q1.z), -dI, S1y);
    S2x = __builtin_elementwise_fma((v2f)(q0.w), inv, S2x);
    S2y = __builtin_elementwise_fma((v2f)(q1.w), -dI, S2y);
    S3x = __builtin_elementwise_fma((v2f)(q1.x), inv, S3x);
    S3y = __builtin_elementwise_fma((v2f)(q2.x), -dI, S3y);
    S4x = __builtin_elementwise_fma((v2f)(q1.y), inv, S4x);
    S4y = __builtin_elementwise_fma((v2f)(q2.y), -dI, S4y);
  }
  const float2 KA = woodbury(make_float2(S1x.x, S1y.x), make_float2(S2x.x, S2y.x),
                             make_float2(S3x.x, S3y.x), make_float2(S4x.x, S4y.x), TA);
  const float2 KB = woodbury(make_float2(S1x.y, S1y.y), make_float2(S2x.y, S2y.y),
                             make_float2(S3x.y, S3y.y), make_float2(S4x.y, S4y.y), TB);
  kt[(size_t)d * 4096 + b] = make_float4(KA.x + KB.x, KA.y + KB.y,
                                         KA.x - KB.x, KA.y - KB.y);
}

// ---------------------------------------------------------------- ifft
// Input is already radix-2'd and digit-reversed -> linear float4 load,
// 6 radix-4 DIT stages in LDS, natural-order real output.
__global__ __launch_bounds__(1024) void ifft_kernel(
    const float4* __restrict__ kt, const float2* __restrict__ tw,
    const float* __restrict__ Din, float* __restrict__ out)
{
  __shared__ __align__(16) float2 xy[LSEQ];   // 64 KB
  const int d = blockIdx.x;
  const int t = threadIdx.x;                  // 0..1023
  const float4* row = kt + (size_t)d * 4096;

  for (int i = t; i < 4096; i += 1024) ((float4*)xy)[i] = row[i];
  __syncthreads();

#pragma unroll
  for (int s = 0; s < 6; ++s) {
    const int h = 2 << (2*s);
    const int twsh = 10 - 2*s;                // tw stride = L/(4h)
#pragma unroll
    for (int j = 0; j < 2; ++j) {
      const int bb = t + (j << 10);           // butterfly id 0..2047
      const int pos = bb & (h - 1);
      const int i0 = ((bb >> (1 + 2*s)) << (3 + 2*s)) + pos;
      const int ti = pos << twsh;
      const float2 w1 = tw[ti];
      const float2 w2 = tw[2*ti];
      const float2 w3 = tw[3*ti];
      const float2 x0 = xy[i0];
      const float2 x1 = xy[i0 + h];
      const float2 x2 = xy[i0 + 2*h];
      const float2 x3 = xy[i0 + 3*h];
      const float2 t1 = cmul(w1, x1);
      const float2 t2 = cmul(w2, x2);
      const float2 t3 = cmul(w3, x3);
      const float2 u0 = make_float2(x0.x + t2.x, x0.y + t2.y);
      const float2 u1 = make_float2(x0.x - t2.x, x0.y - t2.y);
      const float2 u2 = make_float2(t1.x + t3.x, t1.y + t3.y);
      const float2 vv = make_float2(t1.x - t3.x, t1.y - t3.y);
      xy[i0]         = make_float2(u0.x + u2.x, u0.y + u2.y);   // Y0
      xy[i0 + h]     = make_float2(u1.x - vv.y, u1.y + vv.x);   // Y1 = u1 + i*vv
      xy[i0 + 2*h]   = make_float2(u0.x - u2.x, u0.y - u2.y);   // Y2
      xy[i0 + 3*h]   = make_float2(u1.x + vv.y, u1.y - vv.x);   // Y3 = u1 - i*vv
    }
    __syncthreads();
  }

  float* orow = out + (size_t)d * LSEQ;
  for (int i = t; i < LSEQ; i += 1024) orow[i] = xy[i].x;

  // second tuple output: D passthrough (zeros buffer)
  if (d == 0 && t < DMODEL) out[(size_t)DMODEL * LSEQ + t] = Din[t];
}

// ---------------------------------------------------------------- launch
extern "C" void kernel_launch(void* const* d_in, const int* in_sizes, int n_in,
                              void* d_out, int out_size, void* d_ws, size_t ws_size,
                              hipStream_t stream)
{
  const float* Lre    = (const float*)d_in[0];
  const float* Lim    = (const float*)d_in[1];
  const float* Pre    = (const float*)d_in[2];
  const float* Pim    = (const float*)d_in[3];
  const float* Bre    = (const float*)d_in[4];
  const float* Bim    = (const float*)d_in[5];
  const float* log_dt = (const float*)d_in[6];
  const float* Din    = (const float*)d_in[7];
  float* out = (float*)d_out;
  char* ws = (char*)d_ws;

  hipLaunchKernelGGL(precompute_kernel, dim3(64), dim3(256), 0, stream,
                     Lre, Lim, Pre, Pim, Bre, Bim, log_dt, ws);
  hipLaunchKernelGGL(cauchy_kernel, dim3(16, DMODEL), dim3(256), 0, stream,
                     (const float4*)(ws + OFF_DN), (const float*)(ws + OFF_CDT),
                     (float4*)(ws + OFF_KT));
  hipLaunchKernelGGL(ifft_kernel, dim3(DMODEL), dim3(1024), 0, stream,
                     (const float4*)(ws + OFF_KT), (const float2*)(ws + OFF_TW),
                     Din, out);
}

// Round 7
// 125.641 us; speedup vs baseline: 1.1063x; 1.0036x over previous
//
#include <hip/hip_runtime.h>
#include <math.h>

#ifndef M_PI
#define M_PI 3.14159265358979323846
#endif

#define DMODEL 256
#define NSTATE 64
#define LSEQ   8192
#define INVL   (1.0f/8192.0f)

typedef float v2f __attribute__((ext_vector_type(2)));

// Workspace layout (bytes). Total ~17.4 MB.
#define OFF_TW  0                                  // float2[6144]: e^{+2pi i j/L}
#define OFF_DN  (6144*8)                           // float4[2*DMODEL*NSTATE]
#define OFF_CDT (OFF_DN + DMODEL*NSTATE*32)        // float[DMODEL]: 2/dt
#define OFF_KT  (OFF_CDT + 1024)                   // float4[DMODEL*4096]: radix-2'd, digit-reversed K_hat/L

__device__ __forceinline__ float sin_rev(float r) {
#if __has_builtin(__builtin_amdgcn_sinf)
  return __builtin_amdgcn_sinf(r);        // sin(S0 * 2pi)
#else
  return __sinf(r * 6.283185307179586f);
#endif
}
__device__ __forceinline__ float cos_rev(float r) {
#if __has_builtin(__builtin_amdgcn_cosf)
  return __builtin_amdgcn_cosf(r);
#else
  return __cosf(r * 6.283185307179586f);
#endif
}

__device__ __forceinline__ float2 cmul(float2 a, float2 b) {
  return make_float2(a.x*b.x - a.y*b.y, a.x*b.y + a.y*b.x);
}

// K_hat/L from the 4 complex sums. PRB*BRP = S1^2 + S2^2 (complex squares).
// Prefactor 2/(1+z) = 1 + i*T; fold 1/L here.
__device__ __forceinline__ float2 woodbury(float2 S1, float2 S2, float2 S3,
                                           float2 S4, float T) {
  float nr = (S1.x*S1.x - S1.y*S1.y) + (S2.x*S2.x - S2.y*S2.y);
  float ni = 2.0f*(S1.x*S1.y + S2.x*S2.y);
  float dr = 1.0f + S3.x, di = S3.y;
  float inv = __builtin_amdgcn_rcpf(fmaf(dr, dr, di*di));
  float qr = (nr*dr + ni*di) * inv;
  float qi = (ni*dr - nr*di) * inv;
  float vr = S4.x - qr, vi = S4.y - qi;
  return make_float2((vr - T*vi)*INVL, (vi + T*vr)*INVL);
}

// ---------------------------------------------------------------- precompute
__global__ __launch_bounds__(256) void precompute_kernel(
    const float* __restrict__ Lre, const float* __restrict__ Lim,
    const float* __restrict__ Pre, const float* __restrict__ Pim,
    const float* __restrict__ Bre, const float* __restrict__ Bim,
    const float* __restrict__ log_dt, char* __restrict__ ws)
{
  const int t = blockIdx.x * blockDim.x + threadIdx.x;  // 0..16383
  float2* tw  = (float2*)(ws + OFF_TW);
  float4* dn  = (float4*)(ws + OFF_DN);
  float*  cdt = (float*)(ws + OFF_CDT);

  if (t < 6144) {
    double th = (2.0 * M_PI / (double)LSEQ) * (double)t;
    double s, c; sincos(th, &s, &c);
    tw[t] = make_float2((float)c, (float)s);
  }
  {
    float lre = Lre[t], lim = Lim[t];
    float pre = Pre[t], pim = Pim[t];
    float bre = Bre[t], bim = Bim[t];
    float sp = fmaxf(lre, 0.0f) + log1pf(expf(-fabsf(lre)));  // softplus
    float w1r = pre*bre + pim*bim;   // Re conj(P)*B
    float w1i = pre*bim - pim*bre;   // Im conj(P)*B
    float w2  = pre*pre + pim*pim;   // |P|^2
    float w3  = bre*bre + bim*bim;   // |B|^2
    dn[2*t]   = make_float4(lim, sp*sp, sp, 0.0f);
    dn[2*t+1] = make_float4(w1r, w1i, w2, w3);
  }
  if (t < DMODEL) cdt[t] = 2.0f * expf(-log_dt[t]);
}

// ---------------------------------------------------------------- cauchy
// No LDS -> 8 waves/SIMD. Thread = pair (kA, kA+4096), kA digit-reversed.
// A/B points packed lane-wise into v2f (v_pk_* at 2x FP32 rate); TWO
// independent v_rcp per n (no cross-half dependency); Re(r) = sp*inv and
// Im(r) = -dim*inv share inv, so each of the 4 sums is 2 pk-FMAs with a
// single SGPR weight. Writes post-radix-2 {sum, diff} linearly.
__global__ __launch_bounds__(256, 8) void cauchy_kernel(
    const float4* __restrict__ dn_all, const float* __restrict__ cdt,
    float4* __restrict__ kt)
{
  const int d = blockIdx.y;
  const int b = blockIdx.x * 256 + threadIdx.x;   // 0..4095 pair id
  const float4* dn = dn_all + (size_t)d * (2*NSTATE);
  const float c = cdt[d];                         // 2/dt, wave-uniform

  const unsigned r = __brev((unsigned)(2*b)) >> 19;             // 13-bit rev
  const int kA = (int)(((r & 0x0555u) << 1) | ((r & 0x0AAAu) >> 1));  // pair-swap
  // T = tan(pi k/L); (1-z)/(1+z) = i*T, 2/(1+z) = 1 + i*T (exact identities)
  const float rev = (float)kA * (1.0f/16384.0f);  // < 0.25 revolutions
  const float sA = sin_rev(rev), cA = cos_rev(rev);
  float TA =  sA * __builtin_amdgcn_rcpf(cA);
  float TB = -cA * __builtin_amdgcn_rcpf(sA);     // tan(x + pi/2) = -cot(x)
  TA = fminf(fmaxf(TA, -1e7f), 1e7f);
  TB = fminf(fmaxf(TB, -1e7f), 1e7f);
  const v2f g2 = {c * TA, c * TB};                // g purely imaginary, A|B packed

  v2f S1x = {0,0}, S1y = {0,0}, S2x = {0,0}, S2y = {0,0};
  v2f S3x = {0,0}, S3y = {0,0}, S4x = {0,0}, S4y = {0,0};

#pragma unroll 4
  for (int n = 0; n < NSTATE; ++n) {
    const float4 q0 = dn[2*n];      // lam_im, sp^2, sp, 0   (wave-uniform s_load)
    const float4 qw = dn[2*n+1];    // w1r, w1i, w2, w3
    const v2f dim = g2 - q0.x;                                    // pk_add
    const v2f mag = __builtin_elementwise_fma(dim, dim, (v2f)(q0.y)); // pk_fma
    const v2f inv = {__builtin_amdgcn_rcpf(mag.x),
                     __builtin_amdgcn_rcpf(mag.y)};               // 2 indep rcp
    const v2f spinv = q0.z * inv;                                 // Re(r) pair
    const v2f dI    = dim * inv;                                  // -Im(r) pair
    S1x = __builtin_elementwise_fma((v2f)(qw.x), spinv, S1x);
    S1y = __builtin_elementwise_fma((v2f)(qw.x), -dI, S1y);
    S2x = __builtin_elementwise_fma((v2f)(qw.y), spinv, S2x);
    S2y = __builtin_elementwise_fma((v2f)(qw.y), -dI, S2y);
    S3x = __builtin_elementwise_fma((v2f)(qw.z), spinv, S3x);
    S3y = __builtin_elementwise_fma((v2f)(qw.z), -dI, S3y);
    S4x = __builtin_elementwise_fma((v2f)(qw.w), spinv, S4x);
    S4y = __builtin_elementwise_fma((v2f)(qw.w), -dI, S4y);
  }
  const float2 KA = woodbury(make_float2(S1x.x, S1y.x), make_float2(S2x.x, S2y.x),
                             make_float2(S3x.x, S3y.x), make_float2(S4x.x, S4y.x), TA);
  const float2 KB = woodbury(make_float2(S1x.y, S1y.y), make_float2(S2x.y, S2y.y),
                             make_float2(S3x.y, S3y.y), make_float2(S4x.y, S4y.y), TB);
  kt[(size_t)d * 4096 + b] = make_float4(KA.x + KB.x, KA.y + KB.y,
                                         KA.x - KB.x, KA.y - KB.y);
}

// ---------------------------------------------------------------- ifft
// Input is already radix-2'd and digit-reversed -> linear float4 load,
// radix-4 DIT stages in LDS; the LAST stage writes its (final) real parts
// straight to global (coalesced), skipping the LDS round-trip + barrier.
__global__ __launch_bounds__(1024) void ifft_kernel(
    const float4* __restrict__ kt, const float2* __restrict__ tw,
    const float* __restrict__ Din, float* __restrict__ out)
{
  __shared__ __align__(16) float2 xy[LSEQ];   // 64 KB
  const int d = blockIdx.x;
  const int t = threadIdx.x;                  // 0..1023
  const float4* row = kt + (size_t)d * 4096;
  float* orow = out + (size_t)d * LSEQ;

  for (int i = t; i < 4096; i += 1024) ((float4*)xy)[i] = row[i];
  __syncthreads();

#pragma unroll
  for (int s = 0; s < 5; ++s) {
    const int h = 2 << (2*s);
    const int twsh = 10 - 2*s;                // tw stride = L/(4h)
#pragma unroll
    for (int j = 0; j < 2; ++j) {
      const int bb = t + (j << 10);           // butterfly id 0..2047
      const int pos = bb & (h - 1);
      const int i0 = ((bb >> (1 + 2*s)) << (3 + 2*s)) + pos;
      const int ti = pos << twsh;
      const float2 w1 = tw[ti];
      const float2 w2 = tw[2*ti];
      const float2 w3 = tw[3*ti];
      const float2 x0 = xy[i0];
      const float2 x1 = xy[i0 + h];
      const float2 x2 = xy[i0 + 2*h];
      const float2 x3 = xy[i0 + 3*h];
      const float2 t1 = cmul(w1, x1);
      const float2 t2 = cmul(w2, x2);
      const float2 t3 = cmul(w3, x3);
      const float2 u0 = make_float2(x0.x + t2.x, x0.y + t2.y);
      const float2 u1 = make_float2(x0.x - t2.x, x0.y - t2.y);
      const float2 u2 = make_float2(t1.x + t3.x, t1.y + t3.y);
      const float2 vv = make_float2(t1.x - t3.x, t1.y - t3.y);
      xy[i0]         = make_float2(u0.x + u2.x, u0.y + u2.y);   // Y0
      xy[i0 + h]     = make_float2(u1.x - vv.y, u1.y + vv.x);   // Y1 = u1 + i*vv
      xy[i0 + 2*h]   = make_float2(u0.x - u2.x, u0.y - u2.y);   // Y2
      xy[i0 + 3*h]   = make_float2(u1.x + vv.y, u1.y - vv.x);   // Y3 = u1 - i*vv
    }
    __syncthreads();
  }

  // Last stage (h = 2048): outputs are final -> store real parts directly.
#pragma unroll
  for (int j = 0; j < 2; ++j) {
    const int bb = t + (j << 10);             // = pos = i0, 0..2047
    const float2 w1 = tw[bb];
    const float2 w2 = tw[2*bb];
    const float2 w3 = tw[3*bb];
    const float2 x0 = xy[bb];
    const float2 x1 = xy[bb + 2048];
    const float2 x2 = xy[bb + 4096];
    const float2 x3 = xy[bb + 6144];
    const float2 t1 = cmul(w1, x1);
    const float2 t2 = cmul(w2, x2);
    const float2 t3 = cmul(w3, x3);
    const float u0r = x0.x + t2.x, u1r = x0.x - t2.x;
    const float u2r = t1.x + t3.x;
    const float vvi = t1.y - t3.y;            // only Im(v) feeds real outputs
    orow[bb]        = u0r + u2r;              // Re Y0
    orow[bb + 2048] = u1r - vvi;              // Re Y1 = Re(u1 + i*vv)
    orow[bb + 4096] = u0r - u2r;              // Re Y2
    orow[bb + 6144] = u1r + vvi;              // Re Y3 = Re(u1 - i*vv)
  }

  // second tuple output: D passthrough (zeros buffer)
  if (d == 0 && t < DMODEL) out[(size_t)DMODEL * LSEQ + t] = Din[t];
}

// ---------------------------------------------------------------- launch
extern "C" void kernel_launch(void* const* d_in, const int* in_sizes, int n_in,
                              void* d_out, int out_size, void* d_ws, size_t ws_size,
                              hipStream_t stream)
{
  const float* Lre    = (const float*)d_in[0];
  const float* Lim    = (const float*)d_in[1];
  const float* Pre    = (const float*)d_in[2];
  const float* Pim    = (const float*)d_in[3];
  const float* Bre    = (const float*)d_in[4];
  const float* Bim    = (const float*)d_in[5];
  const float* log_dt = (const float*)d_in[6];
  const float* Din    = (const float*)d_in[7];
  float* out = (float*)d_out;
  char* ws = (char*)d_ws;

  hipLaunchKernelGGL(precompute_kernel, dim3(64), dim3(256), 0, stream,
                     Lre, Lim, Pre, Pim, Bre, Bim, log_dt, ws);
  hipLaunchKernelGGL(cauchy_kernel, dim3(16, DMODEL), dim3(256), 0, stream,
                     (const float4*)(ws + OFF_DN), (const float*)(ws + OFF_CDT),
                     (float4*)(ws + OFF_KT));
  hipLaunchKernelGGL(ifft_kernel, dim3(DMODEL), dim3(1024), 0, stream,
                     (const float4*)(ws + OFF_KT), (const float2*)(ws + OFF_TW),
                     Din, out);
}